// Round 1
// baseline (1015.448 us; speedup 1.0000x reference)
//
#include <hip/hip_runtime.h>

#define BB 16
#define NN 2048
#define MM 2048
#define EPSF 1e-9f

constexpr int WAVES = 4;   // waves per block
constexpr int RB = 8;      // rows per wave (row passes)
constexpr int CB = 8;      // cols per wave (col pass)

// ---------------- init: AoS->SoA transpose + state init ----------------
__global__ __launch_bounds__(256) void init_kernel(
    const float* __restrict__ xyz1, const float* __restrict__ xyz2,
    float* __restrict__ X1x, float* __restrict__ X1y, float* __restrict__ X1z,
    float* __restrict__ X2x, float* __restrict__ X2y, float* __restrict__ X2z,
    float* __restrict__ remL, float* __restrict__ remR,
    float* __restrict__ out)
{
    const int t = blockIdx.x * 256 + threadIdx.x;
    if (t < BB * NN) {
        X1x[t] = xyz1[3*t+0]; X1y[t] = xyz1[3*t+1]; X1z[t] = xyz1[3*t+2];
        remL[t] = 1.0f;   // max(n,m)/n
    }
    if (t < BB * MM) {
        X2x[t] = xyz2[3*t+0]; X2y[t] = xyz2[3*t+1]; X2z[t] = xyz2[3*t+2];
        remR[t] = 1.0f;   // max(n,m)/m
    }
    if (t < BB) out[t] = 0.0f;
}

// ---------------- row pass ----------------
// MODE 0: first pass. rowsum at coefNext only (remL == 1 from init).
// MODE 1: fused remainL-update (level j, via e_next^4) + new scale (level j+1).
// MODE 2: last fused pass: e_prev = exp2(coefPrev*d2) direct, e_next = 1 (level 0).
template<int MODE>
__global__ __launch_bounds__(256) void row_pass(
    const float* __restrict__ X1x, const float* __restrict__ X1y, const float* __restrict__ X1z,
    const float* __restrict__ X2x, const float* __restrict__ X2y, const float* __restrict__ X2z,
    const float* __restrict__ remR, const float* __restrict__ P,
    float* __restrict__ remL, float* __restrict__ scale,
    float coefPrev, float coefNext)
{
    const int lane = threadIdx.x & 63;
    const int wave = threadIdx.x >> 6;
    const int bpb = NN / (WAVES * RB);          // blocks per batch = 64
    const int batch = blockIdx.x / bpb;
    const int rblk  = blockIdx.x % bpb;
    const int r0 = rblk * (WAVES * RB) + wave * RB;

    const float* x1x = X1x + batch * NN;
    const float* x1y = X1y + batch * NN;
    const float* x1z = X1z + batch * NN;

    float px[RB], py[RB], pz[RB], psc[RB];
#pragma unroll
    for (int r = 0; r < RB; ++r) {
        px[r] = x1x[r0 + r]; py[r] = x1y[r0 + r]; pz[r] = x1z[r0 + r];
        psc[r] = (MODE != 0) ? scale[batch * NN + r0 + r] : 0.0f;
    }

    const float* c2x = X2x + batch * MM;
    const float* c2y = X2y + batch * MM;
    const float* c2z = X2z + batch * MM;
    const float* rr  = remR + batch * MM;
    const float* pp  = P    + batch * MM;

    float u[RB], rs[RB];
#pragma unroll
    for (int r = 0; r < RB; ++r) { u[r] = 0.0f; rs[r] = 0.0f; }

    for (int c = lane; c < MM; c += 64) {
        const float bx = c2x[c], by = c2y[c], bz = c2z[c];
        const float Rn = rr[c];
        const float Pc = (MODE != 0) ? pp[c] : 0.0f;
#pragma unroll
        for (int r = 0; r < RB; ++r) {
            const float dx = px[r] - bx, dy = py[r] - by, dz = pz[r] - bz;
            const float d2 = dx*dx + dy*dy + dz*dz;
            if (MODE == 0) {
                rs[r] = fmaf(__builtin_amdgcn_exp2f(coefNext * d2), Rn, rs[r]);
            } else if (MODE == 1) {
                const float en = __builtin_amdgcn_exp2f(coefNext * d2);
                const float e2 = en * en;
                u[r]  = fmaf(e2 * e2, Pc, u[r]);   // e_prev = e_next^4
                rs[r] = fmaf(en, Rn, rs[r]);
            } else {
                const float ep = __builtin_amdgcn_exp2f(coefPrev * d2);
                u[r]  = fmaf(ep, Pc, u[r]);
                rs[r] += Rn;                        // e_next = exp(0) = 1
            }
        }
    }

#pragma unroll
    for (int r = 0; r < RB; ++r) {
#pragma unroll
        for (int off = 32; off > 0; off >>= 1) {
            rs[r] += __shfl_xor(rs[r], off, 64);
            if (MODE != 0) u[r] += __shfl_xor(u[r], off, 64);
        }
    }

#pragma unroll
    for (int r = 0; r < RB; ++r) {
        if (lane == r) {
            const int row = batch * NN + r0 + r;
            float L;
            if (MODE == 0) {
                L = remL[row];
            } else {
                L = fmaxf(remL[row] - psc[r] * u[r], 0.0f);
                remL[row] = L;
            }
            scale[row] = L / (rs[r] + EPSF);
        }
    }
}

// ---------------- col pass ----------------
__global__ __launch_bounds__(256) void col_pass(
    const float* __restrict__ X1x, const float* __restrict__ X1y, const float* __restrict__ X1z,
    const float* __restrict__ X2x, const float* __restrict__ X2y, const float* __restrict__ X2z,
    const float* __restrict__ scale,
    float* __restrict__ remR, float* __restrict__ P,
    float* __restrict__ out, float coef)
{
    const int lane = threadIdx.x & 63;
    const int wave = threadIdx.x >> 6;
    const int bpb = MM / (WAVES * CB);          // 64
    const int batch = blockIdx.x / bpb;
    const int cblk  = blockIdx.x % bpb;
    const int c0 = cblk * (WAVES * CB) + wave * CB;

    const float* x2x = X2x + batch * MM;
    const float* x2y = X2y + batch * MM;
    const float* x2z = X2z + batch * MM;

    float qx[CB], qy[CB], qz[CB];
#pragma unroll
    for (int cc = 0; cc < CB; ++cc) {
        qx[cc] = x2x[c0 + cc]; qy[cc] = x2y[c0 + cc]; qz[cc] = x2z[c0 + cc];
    }

    const float* x1x = X1x + batch * NN;
    const float* x1y = X1y + batch * NN;
    const float* x1z = X1z + batch * NN;
    const float* sc  = scale + batch * NN;

    float s[CB], t[CB];
#pragma unroll
    for (int cc = 0; cc < CB; ++cc) { s[cc] = 0.0f; t[cc] = 0.0f; }

    for (int i = lane; i < NN; i += 64) {
        const float ax = x1x[i], ay = x1y[i], az = x1z[i];
        const float si = sc[i];
#pragma unroll
        for (int cc = 0; cc < CB; ++cc) {
            const float dx = ax - qx[cc], dy = ay - qy[cc], dz = az - qz[cc];
            const float d2 = dx*dx + dy*dy + dz*dz;
            const float e  = __builtin_amdgcn_exp2f(coef * d2);
            const float se = si * e;
            s[cc] += se;
            t[cc] = fmaf(se, __builtin_amdgcn_sqrtf(d2), t[cc]);
        }
    }

#pragma unroll
    for (int cc = 0; cc < CB; ++cc) {
#pragma unroll
        for (int off = 32; off > 0; off >>= 1) {
            s[cc] += __shfl_xor(s[cc], off, 64);
            t[cc] += __shfl_xor(t[cc], off, 64);
        }
    }

    float costw = 0.0f;
#pragma unroll
    for (int cc = 0; cc < CB; ++cc) {
        if (lane == cc) {
            const int col = batch * MM + c0 + cc;
            const float R = remR[col];
            const float sumr = s[cc] * R;
            const float cons = fminf(R / (sumr + EPSF), 1.0f);
            costw = R * cons * t[cc];
            P[col] = R * cons;
            remR[col] = fmaxf(R - sumr * cons, 0.0f);
        }
    }
#pragma unroll
    for (int off = 32; off > 0; off >>= 1) costw += __shfl_xor(costw, off, 64);
    if (lane == 0) atomicAdd(out + batch, costw);
}

extern "C" void kernel_launch(void* const* d_in, const int* in_sizes, int n_in,
                              void* d_out, int out_size, void* d_ws, size_t ws_size,
                              hipStream_t stream)
{
    const float* xyz1 = (const float*)d_in[0];
    const float* xyz2 = (const float*)d_in[1];
    float* out = (float*)d_out;
    float* w = (float*)d_ws;

    const int BN = BB * NN, BM = BB * MM;
    float* X1x = w;           float* X1y = X1x + BN;   float* X1z = X1y + BN;
    float* X2x = X1z + BN;    float* X2y = X2x + BM;   float* X2z = X2y + BM;
    float* remL = X2z + BM;   float* scale = remL + BN;
    float* remR = scale + BN; float* P = remR + BM;

    init_kernel<<<dim3((BN + 255) / 256), dim3(256), 0, stream>>>(
        xyz1, xyz2, X1x, X1y, X1z, X2x, X2y, X2z, remL, remR, out);

    // levels: j = 7..-1 -> -(4^j), then 0.  coef = level * log2(e)
    float coef[10];
    const double lv[10] = {-16384.0, -4096.0, -1024.0, -256.0, -64.0,
                           -16.0, -4.0, -1.0, -0.25, 0.0};
    for (int i = 0; i < 10; ++i) coef[i] = (float)(lv[i] * 1.4426950408889634);

    dim3 grid(BB * (NN / (WAVES * RB)));   // 1024
    dim3 blk(256);

    row_pass<0><<<grid, blk, 0, stream>>>(X1x,X1y,X1z, X2x,X2y,X2z, remR, P,
                                          remL, scale, 0.0f, coef[0]);
    for (int j = 0; j < 10; ++j) {
        col_pass<<<grid, blk, 0, stream>>>(X1x,X1y,X1z, X2x,X2y,X2z, scale,
                                           remR, P, out, coef[j]);
        if (j < 8) {
            row_pass<1><<<grid, blk, 0, stream>>>(X1x,X1y,X1z, X2x,X2y,X2z, remR, P,
                                                  remL, scale, coef[j], coef[j+1]);
        } else if (j == 8) {
            row_pass<2><<<grid, blk, 0, stream>>>(X1x,X1y,X1z, X2x,X2y,X2z, remR, P,
                                                  remL, scale, coef[8], 0.0f);
        }
    }
}